// Round 1
// baseline (290.969 us; speedup 1.0000x reference)
//
#include <hip/hip_runtime.h>

#define N_NODES 50000
#define N_EDGES 800000
#define D_INF 64
#define D_HIDF 128

// agg = x  (EPS = 0 -> h = agg + 1.0*x, folded into the init)
__global__ void init_agg_kernel(const float* __restrict__ x, float* __restrict__ agg) {
    int i = blockIdx.x * blockDim.x + threadIdx.x;  // over N*64/4 float4s
    int n4 = N_NODES * D_INF / 4;
    if (i < n4) {
        reinterpret_cast<float4*>(agg)[i] = reinterpret_cast<const float4*>(x)[i];
    }
}

// W1T[j*64 + l] = W1[l*128 + j]  (so the MLP's l-loop reads consecutive floats)
__global__ void transpose_w1_kernel(const float* __restrict__ W1, float* __restrict__ W1T) {
    int i = blockIdx.x * blockDim.x + threadIdx.x;
    if (i < D_INF * D_HIDF) {
        int l = i / D_HIDF;
        int j = i % D_HIDF;
        W1T[j * D_INF + l] = W1[i];
    }
}

// One thread per (edge, feature): 64 consecutive tids = one wave = one edge.
// x-row load is coalesced (256B), atomics go to 64 consecutive floats of agg.
__global__ void scatter_kernel(const float* __restrict__ x,
                               const int* __restrict__ src,
                               const int* __restrict__ dst,
                               float* __restrict__ agg) {
    int tid = blockIdx.x * blockDim.x + threadIdx.x;
    int e = tid >> 6;
    int d = tid & 63;
    if (e < N_EDGES) {
        int s = src[e];
        int t = dst[e];
        atomicAdd(&agg[t * D_INF + d], x[s * D_INF + d]);
    }
}

// One thread per node. Weights indexed wave-uniformly -> scalar loads (SGPR
// operands to v_fmac), h[64]+acc[64] in VGPRs.
__global__ void __launch_bounds__(256) mlp_kernel(const float* __restrict__ agg,
                                                  const float* __restrict__ W1T,
                                                  const float* __restrict__ b1,
                                                  const float* __restrict__ W2,
                                                  const float* __restrict__ b2,
                                                  float* __restrict__ out) {
    int n = blockIdx.x * blockDim.x + threadIdx.x;
    if (n >= N_NODES) return;

    float h[D_INF];
    const float4* aggv = reinterpret_cast<const float4*>(agg + n * D_INF);
#pragma unroll
    for (int i = 0; i < D_INF / 4; i++) {
        float4 v = aggv[i];
        h[4 * i + 0] = v.x;
        h[4 * i + 1] = v.y;
        h[4 * i + 2] = v.z;
        h[4 * i + 3] = v.w;
    }

    float acc[D_INF];
#pragma unroll
    for (int d = 0; d < D_INF; d++) acc[d] = b2[d];

#pragma unroll 2
    for (int j = 0; j < D_HIDF; j++) {
        float s = b1[j];
#pragma unroll
        for (int l = 0; l < D_INF; l++) {
            s += h[l] * W1T[j * D_INF + l];   // uniform address -> s_load
        }
        s = fmaxf(s, 0.0f);
#pragma unroll
        for (int d = 0; d < D_INF; d++) {
            acc[d] += s * W2[j * D_INF + d];  // uniform address -> s_load_dwordx16
        }
    }

    float4* outv = reinterpret_cast<float4*>(out + n * D_INF);
#pragma unroll
    for (int i = 0; i < D_INF / 4; i++) {
        outv[i] = make_float4(acc[4 * i + 0], acc[4 * i + 1], acc[4 * i + 2], acc[4 * i + 3]);
    }
}

extern "C" void kernel_launch(void* const* d_in, const int* in_sizes, int n_in,
                              void* d_out, int out_size, void* d_ws, size_t ws_size,
                              hipStream_t stream) {
    const float* x   = (const float*)d_in[0];
    const int* edge  = (const int*)d_in[1];   // [2, E]: src = edge, dst = edge + E
    const float* W1  = (const float*)d_in[2];
    const float* b1  = (const float*)d_in[3];
    const float* W2  = (const float*)d_in[4];
    const float* b2  = (const float*)d_in[5];
    float* out       = (float*)d_out;

    const int* src = edge;
    const int* dst = edge + N_EDGES;

    // Workspace layout: agg [N*64 floats], then W1T [128*64 floats]
    float* agg = (float*)d_ws;
    float* W1T = agg + (size_t)N_NODES * D_INF;

    // 1) agg = x
    {
        int n4 = N_NODES * D_INF / 4;
        int blocks = (n4 + 255) / 256;
        init_agg_kernel<<<blocks, 256, 0, stream>>>(x, agg);
    }
    // 2) W1T = transpose(W1)
    {
        int n = D_INF * D_HIDF;
        int blocks = (n + 255) / 256;
        transpose_w1_kernel<<<blocks, 256, 0, stream>>>(W1, W1T);
    }
    // 3) scatter-add x[src] into agg[dst]
    {
        int work = N_EDGES * D_INF;
        int blocks = (work + 255) / 256;
        scatter_kernel<<<blocks, 256, 0, stream>>>(x, src, dst, agg);
    }
    // 4) fused MLP
    {
        int blocks = (N_NODES + 255) / 256;
        mlp_kernel<<<blocks, 256, 0, stream>>>(agg, W1T, b1, W2, b2, out);
    }
}